// Round 1
// baseline (1093.425 us; speedup 1.0000x reference)
//
#include <hip/hip_runtime.h>
#include <cstddef>

// Problem constants (B=2, T=2048, C=1024, H=16, D=64)
constexpr int T_SEQ   = 2048;
constexpr int C_DIM   = 1024;
constexpr int N_HEADS = 16;
constexpr int H_DIM   = 64;
constexpr int B_SZ    = 2;
constexpr int M_TOT   = B_SZ * T_SEQ;   // 4096 rows for all GEMMs

// ---------------------------------------------------------------------------
// Register-tiled fp32 GEMM body: out[M,N] = A[M,K] @ W[K,N] + bias
// M=4096, N=K=1024. Tile 128x128, BK=16, 256 threads, 8x8 per thread
// (2x2 blocks of 4x4 to keep LDS reads conflict-free).
// HEADSPLIT=1 writes out in [B,H,T,D] layout (for Q/K/V), else row-major.
// ---------------------------------------------------------------------------
template<int HEADSPLIT>
__device__ __forceinline__ void gemm_body(const float* __restrict__ A,
                                          const float* __restrict__ W,
                                          const float* __restrict__ bias,
                                          float* __restrict__ out)
{
    constexpr int BM = 128, BN = 128, BK = 16;
    constexpr int LDA = BM + 4;   // pad: A-transpose LDS writes -> ~2-way max
    constexpr int LDB = BN + 4;
    __shared__ float As[BK][LDA];
    __shared__ float Bs[BK][LDB];

    const int t  = threadIdx.x;
    const int tx = t & 15;        // 0..15 -> N micro index
    const int ty = t >> 4;        // 0..15 -> M micro index
    const int bm = blockIdx.y * BM;
    const int bn = blockIdx.x * BN;

    // A loads: 128 rows x 16 cols = 512 float4; thread does rows ar, ar+64
    const int ar = t >> 2;        // 0..63
    const int ac = t & 3;         // float4 col within BK

    float acc[2][2][4][4] = {};

    const float* Aptr0 = A + (size_t)(bm + ar) * C_DIM + ac * 4;
    const float* Aptr1 = Aptr0 + (size_t)64 * C_DIM;
    const float* Wptr  = W + (size_t)ty * C_DIM + bn + tx * 4;

    for (int kb = 0; kb < C_DIM; kb += BK) {
        const float4 a0 = *(const float4*)(Aptr0 + kb);
        const float4 a1 = *(const float4*)(Aptr1 + kb);
        const float4 b0 = *(const float4*)(Wptr + (size_t)kb * C_DIM);
        const float4 b1 = *(const float4*)(Wptr + (size_t)kb * C_DIM + 64);

        __syncthreads();   // previous iteration's compute must be done
        As[ac*4+0][ar]      = a0.x;
        As[ac*4+1][ar]      = a0.y;
        As[ac*4+2][ar]      = a0.z;
        As[ac*4+3][ar]      = a0.w;
        As[ac*4+0][ar+64]   = a1.x;
        As[ac*4+1][ar+64]   = a1.y;
        As[ac*4+2][ar+64]   = a1.z;
        As[ac*4+3][ar+64]   = a1.w;
        *(float4*)&Bs[ty][tx*4]      = b0;
        *(float4*)&Bs[ty][tx*4 + 64] = b1;
        __syncthreads();

        #pragma unroll
        for (int kk = 0; kk < BK; ++kk) {
            const float4 a0v = *(const float4*)&As[kk][ty*4];
            const float4 a1v = *(const float4*)&As[kk][ty*4 + 64];
            const float4 b0v = *(const float4*)&Bs[kk][tx*4];
            const float4 b1v = *(const float4*)&Bs[kk][tx*4 + 64];
            const float av[2][4] = {{a0v.x,a0v.y,a0v.z,a0v.w},
                                    {a1v.x,a1v.y,a1v.z,a1v.w}};
            const float bv[2][4] = {{b0v.x,b0v.y,b0v.z,b0v.w},
                                    {b1v.x,b1v.y,b1v.z,b1v.w}};
            #pragma unroll
            for (int ia = 0; ia < 2; ++ia)
                #pragma unroll
                for (int i = 0; i < 4; ++i)
                    #pragma unroll
                    for (int ib = 0; ib < 2; ++ib)
                        #pragma unroll
                        for (int j = 0; j < 4; ++j)
                            acc[ia][ib][i][j] =
                                fmaf(av[ia][i], bv[ib][j], acc[ia][ib][i][j]);
        }
    }

    float4 biasv[2];
    biasv[0] = *(const float4*)&bias[bn + tx*4];
    biasv[1] = *(const float4*)&bias[bn + tx*4 + 64];

    #pragma unroll
    for (int ia = 0; ia < 2; ++ia) {
        #pragma unroll
        for (int i = 0; i < 4; ++i) {
            const int m = bm + ia*64 + ty*4 + i;
            #pragma unroll
            for (int ib = 0; ib < 2; ++ib) {
                const int n = bn + ib*64 + tx*4;
                const float* bp = (const float*)&biasv[ib];
                float4 r;
                r.x = acc[ia][ib][i][0] + bp[0];
                r.y = acc[ia][ib][i][1] + bp[1];
                r.z = acc[ia][ib][i][2] + bp[2];
                r.w = acc[ia][ib][i][3] + bp[3];
                if (HEADSPLIT) {
                    // out[b][h][t][d], m = b*T + t, n = h*64 + d
                    const int bb = m >> 11;            // m / T_SEQ
                    const int tq = m & (T_SEQ - 1);
                    const int h  = n >> 6;
                    const int d  = n & 63;
                    *(float4*)&out[(((size_t)(bb*N_HEADS + h))*T_SEQ + tq)*H_DIM + d] = r;
                } else {
                    *(float4*)&out[(size_t)m * C_DIM + n] = r;
                }
            }
        }
    }
}

__global__ __launch_bounds__(256)
void qkv_proj_kernel(const float* __restrict__ x,
                     const float* __restrict__ Wq, const float* __restrict__ bq,
                     const float* __restrict__ Wk, const float* __restrict__ bk,
                     const float* __restrict__ Wv, const float* __restrict__ bv,
                     float* __restrict__ q, float* __restrict__ k,
                     float* __restrict__ v)
{
    const float* W; const float* bias; float* out;
    if (blockIdx.z == 0)      { W = Wq; bias = bq; out = q; }
    else if (blockIdx.z == 1) { W = Wk; bias = bk; out = k; }
    else                      { W = Wv; bias = bv; out = v; }
    gemm_body<1>(x, W, bias, out);
}

__global__ __launch_bounds__(256)
void out_proj_kernel(const float* __restrict__ A,
                     const float* __restrict__ Wo, const float* __restrict__ bo,
                     float* __restrict__ out)
{
    gemm_body<0>(A, Wo, bo, out);
}

// ---------------------------------------------------------------------------
// Flash-style causal attention. One block = one (b,h) and 64 Q rows.
// 256 threads; S and PV register-tiled 4x4 per thread (16x16 thread grid).
// Online softmax (m, l per row, replicated over the 16 lanes of a row group).
// LDS: Q, K, V tiles 64x64 fp32 (padded). P reuses K's LDS (after S-compute).
// ---------------------------------------------------------------------------
__global__ __launch_bounds__(256)
void attn_kernel(const float* __restrict__ q, const float* __restrict__ k,
                 const float* __restrict__ v, float* __restrict__ att)
{
    constexpr int LD = H_DIM + 4;   // 68: conflict-free padded stride
    __shared__ float Qs[64][LD];
    __shared__ float Ks[64][LD];
    __shared__ float Vs[64][LD];
    float (*Ps)[LD] = Ks;           // P overwrites K after S is computed

    const int t  = threadIdx.x;
    const int tx = t & 15;          // key/col micro index
    const int ty = t >> 4;          // query/row micro index
    const int qt = blockIdx.x;      // q tile: rows qt*64 .. +63
    const int bh = blockIdx.y;      // b*16 + h
    const int q0 = qt * 64;
    const size_t base = (size_t)bh * T_SEQ * H_DIM;

    // Load Q tile (rows q0..q0+63, 64 cols)
    {
        const int rr = t >> 4, c4 = t & 15;
        #pragma unroll
        for (int it = 0; it < 4; ++it) {
            const int row = rr + it*16;
            *(float4*)&Qs[row][c4*4] =
                *(const float4*)&q[base + (size_t)(q0 + row)*H_DIM + c4*4];
        }
    }

    float m_i[4], l_i[4];
    float4 O4[4];
    #pragma unroll
    for (int i = 0; i < 4; ++i) {
        m_i[i] = -1e30f; l_i[i] = 0.f;
        O4[i] = make_float4(0.f, 0.f, 0.f, 0.f);
    }

    for (int j = 0; j <= qt; ++j) {
        __syncthreads();   // prev iter's PV (reads Ps=Ks, Vs) done
        {
            const int rr = t >> 4, c4 = t & 15;
            #pragma unroll
            for (int it = 0; it < 4; ++it) {
                const int row = rr + it*16;
                *(float4*)&Ks[row][c4*4] =
                    *(const float4*)&k[base + (size_t)(j*64 + row)*H_DIM + c4*4];
                *(float4*)&Vs[row][c4*4] =
                    *(const float4*)&v[base + (size_t)(j*64 + row)*H_DIM + c4*4];
            }
        }
        __syncthreads();

        // S = (Q K^T) / 8 ; thread rows ty*4+i, cols tx*4+jj
        float s[4][4] = {};
        #pragma unroll
        for (int d4 = 0; d4 < 16; ++d4) {
            float4 qv[4], kv[4];
            #pragma unroll
            for (int i = 0; i < 4; ++i)
                qv[i] = *(const float4*)&Qs[ty*4 + i][d4*4];
            #pragma unroll
            for (int jj = 0; jj < 4; ++jj)
                kv[jj] = *(const float4*)&Ks[tx*4 + jj][d4*4];
            #pragma unroll
            for (int i = 0; i < 4; ++i)
                #pragma unroll
                for (int jj = 0; jj < 4; ++jj) {
                    s[i][jj] = fmaf(qv[i].x, kv[jj].x, s[i][jj]);
                    s[i][jj] = fmaf(qv[i].y, kv[jj].y, s[i][jj]);
                    s[i][jj] = fmaf(qv[i].z, kv[jj].z, s[i][jj]);
                    s[i][jj] = fmaf(qv[i].w, kv[jj].w, s[i][jj]);
                }
        }

        const bool diag = (j == qt);
        float p[4][4];
        #pragma unroll
        for (int i = 0; i < 4; ++i) {
            float tm = -1e30f;
            #pragma unroll
            for (int jj = 0; jj < 4; ++jj) {
                s[i][jj] *= 0.125f;
                if (diag && (tx*4 + jj > ty*4 + i)) s[i][jj] = -1e30f;
                tm = fmaxf(tm, s[i][jj]);
            }
            // row max across the 16 lanes of this row group
            #pragma unroll
            for (int off = 1; off < 16; off <<= 1)
                tm = fmaxf(tm, __shfl_xor(tm, off));
            const float mn = fmaxf(m_i[i], tm);
            const float sc = __expf(m_i[i] - mn);
            m_i[i] = mn;
            float rs = 0.f;
            #pragma unroll
            for (int jj = 0; jj < 4; ++jj) {
                p[i][jj] = __expf(s[i][jj] - mn);
                rs += p[i][jj];
            }
            #pragma unroll
            for (int off = 1; off < 16; off <<= 1)
                rs += __shfl_xor(rs, off);
            l_i[i] = l_i[i]*sc + rs;
            O4[i].x *= sc; O4[i].y *= sc; O4[i].z *= sc; O4[i].w *= sc;
        }

        __syncthreads();   // all threads done reading Ks (S-compute)
        #pragma unroll
        for (int i = 0; i < 4; ++i)
            *(float4*)&Ps[ty*4 + i][tx*4] =
                make_float4(p[i][0], p[i][1], p[i][2], p[i][3]);
        __syncthreads();   // P visible

        // O += P V ; thread rows ty*4+i, d cols tx*4..+3
        #pragma unroll
        for (int k4 = 0; k4 < 16; ++k4) {
            float4 pv[4], vv[4];
            #pragma unroll
            for (int i = 0; i < 4; ++i)
                pv[i] = *(const float4*)&Ps[ty*4 + i][k4*4];
            #pragma unroll
            for (int u = 0; u < 4; ++u)
                vv[u] = *(const float4*)&Vs[k4*4 + u][tx*4];
            #pragma unroll
            for (int i = 0; i < 4; ++i) {
                const float pp[4] = {pv[i].x, pv[i].y, pv[i].z, pv[i].w};
                #pragma unroll
                for (int u = 0; u < 4; ++u) {
                    O4[i].x = fmaf(pp[u], vv[u].x, O4[i].x);
                    O4[i].y = fmaf(pp[u], vv[u].y, O4[i].y);
                    O4[i].z = fmaf(pp[u], vv[u].z, O4[i].z);
                    O4[i].w = fmaf(pp[u], vv[u].w, O4[i].w);
                }
            }
        }
    }

    // normalize + write merged-head layout [B, T, C]
    const int b = bh >> 4, h = bh & 15;
    #pragma unroll
    for (int i = 0; i < 4; ++i) {
        const float inv = 1.0f / l_i[i];
        float4 r;
        r.x = O4[i].x * inv; r.y = O4[i].y * inv;
        r.z = O4[i].z * inv; r.w = O4[i].w * inv;
        const int row = q0 + ty*4 + i;
        *(float4*)&att[((size_t)(b*T_SEQ + row))*C_DIM + h*H_DIM + tx*4] = r;
    }
}

// ---------------------------------------------------------------------------
extern "C" void kernel_launch(void* const* d_in, const int* in_sizes, int n_in,
                              void* d_out, int out_size, void* d_ws, size_t ws_size,
                              hipStream_t stream) {
    (void)in_sizes; (void)n_in; (void)out_size; (void)ws_size;
    const float* x  = (const float*)d_in[0];
    const float* Wq = (const float*)d_in[1];
    const float* bq = (const float*)d_in[2];
    const float* Wk = (const float*)d_in[3];
    const float* bk = (const float*)d_in[4];
    const float* Wv = (const float*)d_in[5];
    const float* bv = (const float*)d_in[6];
    const float* Wo = (const float*)d_in[7];
    const float* bo = (const float*)d_in[8];

    // workspace: q, k, v in [B,H,T,D] + att in [B,T,C]  (4 x 16 MB = 64 MB)
    float* q   = (float*)d_ws;
    float* k   = q + (size_t)M_TOT * C_DIM;
    float* v   = k + (size_t)M_TOT * C_DIM;
    float* att = v + (size_t)M_TOT * C_DIM;

    dim3 gProj(C_DIM/128, M_TOT/128, 3);   // 8 x 32 x 3
    qkv_proj_kernel<<<gProj, 256, 0, stream>>>(x, Wq, bq, Wk, bk, Wv, bv, q, k, v);

    dim3 gAttn(T_SEQ/64, B_SZ*N_HEADS);     // 32 x 32
    attn_kernel<<<gAttn, 256, 0, stream>>>(q, k, v, att);

    dim3 gOut(C_DIM/128, M_TOT/128);        // 8 x 32
    out_proj_kernel<<<gOut, 256, 0, stream>>>(att, Wo, bo, (float*)d_out);
}

// Round 7
// 581.579 us; speedup vs baseline: 1.8801x; 1.8801x over previous
//
#include <hip/hip_runtime.h>
#include <cstddef>

// Problem constants (B=2, T=2048, C=1024, H=16, D=64)
constexpr int T_SEQ   = 2048;
constexpr int C_DIM   = 1024;
constexpr int N_HEADS = 16;
constexpr int H_DIM   = 64;
constexpr int B_SZ    = 2;
constexpr int M_TOT   = B_SZ * T_SEQ;   // 4096 rows for all GEMMs

typedef __attribute__((ext_vector_type(8))) short bf16x8;
typedef __attribute__((ext_vector_type(4))) float f32x4;

__device__ __forceinline__ ushort f2bf(float x) {
    unsigned u = __float_as_uint(x);
    u = (u + 0x7FFF + ((u >> 16) & 1)) >> 16;   // round-to-nearest-even
    return (ushort)u;
}

// ---------------------------------------------------------------------------
// Register-tiled fp32 GEMM body: out[M,N] = A[M,K] @ W[K,N] + bias
// Tile 128x128, BK=16, 256 threads, 8x8 per thread.
// HEADSPLIT=1 writes bf16 out in [B,H,T,D] layout (Q/K/V); else fp32 row-major.
// ---------------------------------------------------------------------------
template<int HEADSPLIT, typename OutT>
__device__ __forceinline__ void gemm_body(const float* __restrict__ A,
                                          const float* __restrict__ W,
                                          const float* __restrict__ bias,
                                          OutT* __restrict__ out)
{
    constexpr int BM = 128, BN = 128, BK = 16;
    constexpr int LDA = BM + 4;
    constexpr int LDB = BN + 4;
    __shared__ float As[BK][LDA];
    __shared__ float Bs[BK][LDB];

    const int t  = threadIdx.x;
    const int tx = t & 15;
    const int ty = t >> 4;
    const int bm = blockIdx.y * BM;
    const int bn = blockIdx.x * BN;

    const int ar = t >> 2;
    const int ac = t & 3;

    float acc[2][2][4][4] = {};

    const float* Aptr0 = A + (size_t)(bm + ar) * C_DIM + ac * 4;
    const float* Aptr1 = Aptr0 + (size_t)64 * C_DIM;
    const float* Wptr  = W + (size_t)ty * C_DIM + bn + tx * 4;

    for (int kb = 0; kb < C_DIM; kb += BK) {
        const float4 a0 = *(const float4*)(Aptr0 + kb);
        const float4 a1 = *(const float4*)(Aptr1 + kb);
        const float4 b0 = *(const float4*)(Wptr + (size_t)kb * C_DIM);
        const float4 b1 = *(const float4*)(Wptr + (size_t)kb * C_DIM + 64);

        __syncthreads();
        As[ac*4+0][ar]      = a0.x;
        As[ac*4+1][ar]      = a0.y;
        As[ac*4+2][ar]      = a0.z;
        As[ac*4+3][ar]      = a0.w;
        As[ac*4+0][ar+64]   = a1.x;
        As[ac*4+1][ar+64]   = a1.y;
        As[ac*4+2][ar+64]   = a1.z;
        As[ac*4+3][ar+64]   = a1.w;
        *(float4*)&Bs[ty][tx*4]      = b0;
        *(float4*)&Bs[ty][tx*4 + 64] = b1;
        __syncthreads();

        #pragma unroll
        for (int kk = 0; kk < BK; ++kk) {
            const float4 a0v = *(const float4*)&As[kk][ty*4];
            const float4 a1v = *(const float4*)&As[kk][ty*4 + 64];
            const float4 b0v = *(const float4*)&Bs[kk][tx*4];
            const float4 b1v = *(const float4*)&Bs[kk][tx*4 + 64];
            const float av[2][4] = {{a0v.x,a0v.y,a0v.z,a0v.w},
                                    {a1v.x,a1v.y,a1v.z,a1v.w}};
            const float bv[2][4] = {{b0v.x,b0v.y,b0v.z,b0v.w},
                                    {b1v.x,b1v.y,b1v.z,b1v.w}};
            #pragma unroll
            for (int ia = 0; ia < 2; ++ia)
                #pragma unroll
                for (int i = 0; i < 4; ++i)
                    #pragma unroll
                    for (int ib = 0; ib < 2; ++ib)
                        #pragma unroll
                        for (int j = 0; j < 4; ++j)
                            acc[ia][ib][i][j] =
                                fmaf(av[ia][i], bv[ib][j], acc[ia][ib][i][j]);
        }
    }

    float4 biasv[2];
    biasv[0] = *(const float4*)&bias[bn + tx*4];
    biasv[1] = *(const float4*)&bias[bn + tx*4 + 64];

    #pragma unroll
    for (int ia = 0; ia < 2; ++ia) {
        #pragma unroll
        for (int i = 0; i < 4; ++i) {
            const int m = bm + ia*64 + ty*4 + i;
            #pragma unroll
            for (int ib = 0; ib < 2; ++ib) {
                const int n = bn + ib*64 + tx*4;
                const float* bp = (const float*)&biasv[ib];
                float r[4];
                #pragma unroll
                for (int jj = 0; jj < 4; ++jj)
                    r[jj] = acc[ia][ib][i][jj] + bp[jj];
                if (HEADSPLIT) {
                    // bf16 out[b][h][t][d]
                    const int bb = m >> 11;
                    const int tq = m & (T_SEQ - 1);
                    const int h  = n >> 6;
                    const int d  = n & 63;
                    ushort4 rb;
                    rb.x = f2bf(r[0]); rb.y = f2bf(r[1]);
                    rb.z = f2bf(r[2]); rb.w = f2bf(r[3]);
                    *(ushort4*)&((ushort*)out)[(((size_t)(bb*N_HEADS + h))*T_SEQ + tq)*H_DIM + d] = rb;
                } else {
                    *(float4*)&((float*)out)[(size_t)m * C_DIM + n] =
                        make_float4(r[0], r[1], r[2], r[3]);
                }
            }
        }
    }
}

__global__ __launch_bounds__(256)
void qkv_proj_kernel(const float* __restrict__ x,
                     const float* __restrict__ Wq, const float* __restrict__ bq,
                     const float* __restrict__ Wk, const float* __restrict__ bk,
                     const float* __restrict__ Wv, const float* __restrict__ bv,
                     ushort* __restrict__ q, ushort* __restrict__ k,
                     ushort* __restrict__ v)
{
    const float* W; const float* bias; ushort* out;
    if (blockIdx.z == 0)      { W = Wq; bias = bq; out = q; }
    else if (blockIdx.z == 1) { W = Wk; bias = bk; out = k; }
    else                      { W = Wv; bias = bv; out = v; }
    gemm_body<1, ushort>(x, W, bias, out);
}

__global__ __launch_bounds__(256)
void out_proj_kernel(const float* __restrict__ A,
                     const float* __restrict__ Wo, const float* __restrict__ bo,
                     float* __restrict__ out)
{
    gemm_body<0, float>(A, Wo, bo, out);
}

// ---------------------------------------------------------------------------
// bf16-MFMA flash attention.
// Block = 256 threads (4 waves), one (b,h), TWO paired 64-row q-tiles
// (qt = 31-pair first, then pair) -> every block does exactly 33 key-tile
// iterations: perfect balance. Wave w owns q-rows 16w..16w+15.
// LDS tiles 64x64 bf16, XOR chunk-swizzle (chunk ^ (row&7)) => MFMA fragment
// ds_read_b128 are 2-way max (free). P goes through LDS (wave-local rows, no
// barrier). 2 barriers per iteration.
// ---------------------------------------------------------------------------
__global__ __launch_bounds__(256)
void attn_kernel(const ushort* __restrict__ q, const ushort* __restrict__ k,
                 const ushort* __restrict__ v, float* __restrict__ att)
{
    __shared__ ushort Qs[64][64];
    __shared__ ushort Ks[64][64];
    __shared__ ushort Vt[64][64];   // transposed: [d][key]
    __shared__ ushort Ps[64][64];

    const int t    = threadIdx.x;
    const int w    = t >> 6;         // wave 0..3
    const int lane = t & 63;
    const int lhi  = lane >> 4;      // 0..3
    const int llo  = lane & 15;      // 0..15
    const int pair = blockIdx.x;     // 0..15
    const int bh   = blockIdx.y;     // b*16 + h
    const int b    = bh >> 4, h = bh & 15;
    const size_t base = (size_t)bh * T_SEQ * H_DIM;

    #pragma unroll 1
    for (int side = 0; side < 2; ++side) {
        const int qt = side ? pair : (31 - pair);
        const int q0 = qt * 64;

        // ---- stage Q tile (bf16, swizzled). 512 16B-chunks, 2 per thread.
        #pragma unroll
        for (int u = 0; u < 2; ++u) {
            const int idx = t*2 + u;
            const int r = idx >> 3, c = idx & 7;
            const uint4 val = *(const uint4*)&q[base + (size_t)(q0 + r)*H_DIM + c*8];
            *(uint4*)&Qs[r][(c ^ (r & 7)) * 8] = val;
        }

        float m_i[4], l_i[4];
        f32x4 o[4];
        #pragma unroll
        for (int i = 0; i < 4; ++i) {
            m_i[i] = -1e30f; l_i[i] = 0.f;
            o[i] = (f32x4){0.f, 0.f, 0.f, 0.f};
        }

        #pragma unroll 1
        for (int j = 0; j <= qt; ++j) {
            __syncthreads();   // prev iter done reading Ks/Vt
            // ---- stage K tile (row-major) + V tile (transposed), bf16
            #pragma unroll
            for (int u = 0; u < 2; ++u) {
                const int idx = t*2 + u;
                const int r = idx >> 3, c = idx & 7;
                const uint4 kv4 = *(const uint4*)&k[base + (size_t)(j*64 + r)*H_DIM + c*8];
                *(uint4*)&Ks[r][(c ^ (r & 7)) * 8] = kv4;
                const uint4 vv4 = *(const uint4*)&v[base + (size_t)(j*64 + r)*H_DIM + c*8];
                const ushort* ve = (const ushort*)&vv4;
                #pragma unroll
                for (int e = 0; e < 8; ++e) {
                    const int d = c*8 + e;          // row of Vt
                    Vt[d][(((r >> 3) ^ (d & 7)) * 8) + (r & 7)] = ve[e];
                }
            }
            __syncthreads();   // tiles visible

            // ---- S = Q K^T (per wave: rows 16w..16w+15 x 64 keys)
            bf16x8 af[2];
            {
                const int row = 16*w + llo;
                #pragma unroll
                for (int ds = 0; ds < 2; ++ds)
                    af[ds] = *(const bf16x8*)&Qs[row][((ds*4 + lhi) ^ (row & 7)) * 8];
            }
            f32x4 sacc[4];
            #pragma unroll
            for (int kt = 0; kt < 4; ++kt) {
                sacc[kt] = (f32x4){0.f, 0.f, 0.f, 0.f};
                const int krow = kt*16 + llo;
                #pragma unroll
                for (int ds = 0; ds < 2; ++ds) {
                    const bf16x8 bf = *(const bf16x8*)&Ks[krow][((ds*4 + lhi) ^ (krow & 7)) * 8];
                    sacc[kt] = __builtin_amdgcn_mfma_f32_16x16x32_bf16(af[ds], bf, sacc[kt], 0, 0, 0);
                }
            }

            // ---- online softmax (lane holds 4 qrows x 1 key per key-subtile)
            float p[4][4];     // [kt][reg]
            float rm[4];
            #pragma unroll
            for (int reg = 0; reg < 4; ++reg) {
                const int qr = q0 + 16*w + lhi*4 + reg;
                float tm = -1e30f;
                #pragma unroll
                for (int kt = 0; kt < 4; ++kt) {
                    float sv = sacc[kt][reg] * 0.125f;
                    const int keyg = j*64 + kt*16 + llo;
                    sv = (keyg <= qr) ? sv : -1e30f;
                    p[kt][reg] = sv;
                    tm = fmaxf(tm, sv);
                }
                #pragma unroll
                for (int off = 1; off < 16; off <<= 1)
                    tm = fmaxf(tm, __shfl_xor(tm, off));
                rm[reg] = tm;
            }
            #pragma unroll
            for (int reg = 0; reg < 4; ++reg) {
                const float mn = fmaxf(m_i[reg], rm[reg]);
                const float sc = __expf(m_i[reg] - mn);
                m_i[reg] = mn;
                float acc = 0.f;
                #pragma unroll
                for (int kt = 0; kt < 4; ++kt) {
                    const float pe = __expf(p[kt][reg] - mn);
                    p[kt][reg] = pe;
                    acc += pe;
                }
                #pragma unroll
                for (int off = 1; off < 16; off <<= 1)
                    acc += __shfl_xor(acc, off);
                l_i[reg] = l_i[reg]*sc + acc;
                #pragma unroll
                for (int dt = 0; dt < 4; ++dt)
                    o[dt][reg] *= sc;
            }

            // ---- write P (bf16, swizzled). Rows 16w.. are wave-local.
            #pragma unroll
            for (int kt = 0; kt < 4; ++kt) {
                #pragma unroll
                for (int reg = 0; reg < 4; ++reg) {
                    const int row = 16*w + lhi*4 + reg;
                    const int key = kt*16 + llo;
                    Ps[row][(((key >> 3) ^ (row & 7)) * 8) + (key & 7)] =
                        f2bf(p[kt][reg]);
                }
            }

            // ---- O += P V (A=P from LDS, B=Vt from LDS)
            bf16x8 pf[2];
            {
                const int row = 16*w + llo;
                #pragma unroll
                for (int ks = 0; ks < 2; ++ks)
                    pf[ks] = *(const bf16x8*)&Ps[row][((ks*4 + lhi) ^ (row & 7)) * 8];
            }
            #pragma unroll
            for (int dt = 0; dt < 4; ++dt) {
                const int vrow = dt*16 + llo;
                #pragma unroll
                for (int ks = 0; ks < 2; ++ks) {
                    const bf16x8 bf = *(const bf16x8*)&Vt[vrow][((ks*4 + lhi) ^ (vrow & 7)) * 8];
                    o[dt] = __builtin_amdgcn_mfma_f32_16x16x32_bf16(pf[ks], bf, o[dt], 0, 0, 0);
                }
            }
        }

        // ---- normalize + write [B,T,C] fp32
        #pragma unroll
        for (int reg = 0; reg < 4; ++reg) {
            const float inv = 1.0f / l_i[reg];
            const int row = q0 + 16*w + lhi*4 + reg;
            #pragma unroll
            for (int dt = 0; dt < 4; ++dt)
                att[((size_t)(b*T_SEQ + row))*C_DIM + h*H_DIM + dt*16 + llo] =
                    o[dt][reg] * inv;
        }
        __syncthreads();   // side 0 fully done before restaging
    }
}

// ---------------------------------------------------------------------------
extern "C" void kernel_launch(void* const* d_in, const int* in_sizes, int n_in,
                              void* d_out, int out_size, void* d_ws, size_t ws_size,
                              hipStream_t stream) {
    (void)in_sizes; (void)n_in; (void)out_size; (void)ws_size;
    const float* x  = (const float*)d_in[0];
    const float* Wq = (const float*)d_in[1];
    const float* bq = (const float*)d_in[2];
    const float* Wk = (const float*)d_in[3];
    const float* bk = (const float*)d_in[4];
    const float* Wv = (const float*)d_in[5];
    const float* bv = (const float*)d_in[6];
    const float* Wo = (const float*)d_in[7];
    const float* bo = (const float*)d_in[8];

    // workspace: q,k,v bf16 [B,H,T,D] (8 MB each) + att f32 [B,T,C] (16 MB)
    ushort* q = (ushort*)d_ws;
    ushort* k = q + (size_t)M_TOT * C_DIM;
    ushort* v = k + (size_t)M_TOT * C_DIM;
    float* att = (float*)(v + (size_t)M_TOT * C_DIM);

    dim3 gProj(C_DIM/128, M_TOT/128, 3);
    qkv_proj_kernel<<<gProj, 256, 0, stream>>>(x, Wq, bq, Wk, bk, Wv, bv, q, k, v);

    dim3 gAttn(16, B_SZ*N_HEADS);          // 16 balanced pairs x 32 (b,h)
    attn_kernel<<<gAttn, 256, 0, stream>>>(q, k, v, att);

    dim3 gOut(C_DIM/128, M_TOT/128);
    out_proj_kernel<<<gOut, 256, 0, stream>>>(att, Wo, bo, (float*)d_out);
}

// Round 9
// 292.859 us; speedup vs baseline: 3.7336x; 1.9859x over previous
//
#include <hip/hip_runtime.h>
#include <cstddef>

// Problem constants (B=2, T=2048, C=1024, H=16, D=64)
constexpr int T_SEQ   = 2048;
constexpr int C_DIM   = 1024;
constexpr int N_HEADS = 16;
constexpr int H_DIM   = 64;
constexpr int B_SZ    = 2;
constexpr int M_TOT   = B_SZ * T_SEQ;   // 4096 rows for all GEMMs

typedef __attribute__((ext_vector_type(8))) short bf16x8;
typedef __attribute__((ext_vector_type(4))) float f32x4;

__device__ __forceinline__ ushort f2bf(float x) {
    unsigned u = __float_as_uint(x);
    u = (u + 0x7FFF + ((u >> 16) & 1)) >> 16;   // round-to-nearest-even
    return (ushort)u;
}
__device__ __forceinline__ float bf2f(ushort h) {
    return __uint_as_float((unsigned)h << 16);
}
__device__ __forceinline__ void split2(float x, ushort& h, ushort& l) {
    h = f2bf(x);
    l = f2bf(x - bf2f(h));      // residual; hi+lo ~ fp32 (rel err ~2^-17)
}

// ---------------------------------------------------------------------------
// convert_x: fp32 [M,C] -> hi/lo bf16 [M,C]. 4 elems/thread.
// ---------------------------------------------------------------------------
__global__ __launch_bounds__(256)
void convert_x_kernel(const float* __restrict__ x,
                      ushort* __restrict__ xh, ushort* __restrict__ xl)
{
    const int i = blockIdx.x * 256 + threadIdx.x;
    const float4 v = ((const float4*)x)[i];
    ushort4 h, l;
    split2(v.x, h.x, l.x); split2(v.y, h.y, l.y);
    split2(v.z, h.z, l.z); split2(v.w, h.w, l.w);
    ((ushort4*)xh)[i] = h;
    ((ushort4*)xl)[i] = l;
}

// ---------------------------------------------------------------------------
// convert_w: W [k][n] fp32 -> Wt [n][k] hi/lo bf16 (LDS-tiled transpose).
// z selects matrix (Wq,Wk,Wv,Wo); outputs concatenated per-matrix.
// ---------------------------------------------------------------------------
__global__ __launch_bounds__(256)
void convert_w_kernel(const float* __restrict__ Wq, const float* __restrict__ Wk,
                      const float* __restrict__ Wv, const float* __restrict__ Wo,
                      ushort* __restrict__ wth, ushort* __restrict__ wtl)
{
    __shared__ float Tt[64][65];
    const float* W = (blockIdx.z == 0) ? Wq : (blockIdx.z == 1) ? Wk :
                     (blockIdx.z == 2) ? Wv : Wo;
    ushort* th = wth + (size_t)blockIdx.z * C_DIM * C_DIM;
    ushort* tl = wtl + (size_t)blockIdx.z * C_DIM * C_DIM;
    const int t = threadIdx.x, tx = t & 15, ty = t >> 4;
    const int bk = blockIdx.x * 64, bn = blockIdx.y * 64;
    #pragma unroll
    for (int it = 0; it < 4; ++it) {
        const int kk = ty + it * 16;
        const float4 v = *(const float4*)&W[(size_t)(bk + kk) * C_DIM + bn + tx*4];
        Tt[kk][tx*4+0] = v.x; Tt[kk][tx*4+1] = v.y;
        Tt[kk][tx*4+2] = v.z; Tt[kk][tx*4+3] = v.w;
    }
    __syncthreads();
    #pragma unroll
    for (int it = 0; it < 4; ++it) {
        const int nn = ty + it * 16;
        ushort4 h, l;
        split2(Tt[tx*4+0][nn], h.x, l.x);
        split2(Tt[tx*4+1][nn], h.y, l.y);
        split2(Tt[tx*4+2][nn], h.z, l.z);
        split2(Tt[tx*4+3][nn], h.w, l.w);
        *(ushort4*)&th[(size_t)(bn+nn)*C_DIM + bk + tx*4] = h;
        *(ushort4*)&tl[(size_t)(bn+nn)*C_DIM + bk + tx*4] = l;
    }
}

// ---------------------------------------------------------------------------
// Split-bf16 MFMA GEMM: out[M,N] = (Ah+Al)[M,K] @ (Bh+Bl)^T[N,K]^T + bias
// via Ah@Bh + Ah@Bl + Al@Bh (fp32 MFMA accumulation = ~fp32 GEMM precision).
// Tile 128x128, BK=64, 256 threads = 4 waves, wave = 64x64 sub-tile (4x4
// fragments of 16x16x32). LDS chunk-swizzle (chunk ^ (row&7)): conflict-free.
// OUT_MODE 1: bf16 headsplit [B,H,T,D]; OUT_MODE 0: fp32 row-major.
// ---------------------------------------------------------------------------
template<int OUT_MODE>
__device__ __forceinline__ void split_gemm(const ushort* __restrict__ Ah,
                                           const ushort* __restrict__ Al,
                                           const ushort* __restrict__ Bth,
                                           const ushort* __restrict__ Btl,
                                           const float* __restrict__ bias,
                                           void* __restrict__ out)
{
    __shared__ ushort sAh[128][64];
    __shared__ ushort sAl[128][64];
    __shared__ ushort sBh[128][64];
    __shared__ ushort sBl[128][64];

    const int t = threadIdx.x;
    const int lane = t & 63, wv = t >> 6;
    const int llo = lane & 15, lhi = lane >> 4;
    const int wr = wv >> 1, wc = wv & 1;
    const int bm = blockIdx.y * 128, bn = blockIdx.x * 128;

    f32x4 acc[4][4];
    #pragma unroll
    for (int i = 0; i < 4; ++i)
        #pragma unroll
        for (int j = 0; j < 4; ++j)
            acc[i][j] = (f32x4){0.f, 0.f, 0.f, 0.f};

    for (int kb = 0; kb < C_DIM; kb += 64) {
        __syncthreads();     // prev iteration done reading LDS
        #pragma unroll
        for (int it = 0; it < 4; ++it) {
            const int p = it * 256 + t;        // chunk id 0..1023
            const int r = p >> 3, c = p & 7;   // row, 16B-chunk col
            const int sc = (c ^ (r & 7)) * 8;  // swizzled element offset
            const size_t ga = (size_t)(bm + r) * C_DIM + kb + c * 8;
            const size_t gb = (size_t)(bn + r) * C_DIM + kb + c * 8;
            *(uint4*)&sAh[r][sc] = *(const uint4*)&Ah[ga];
            *(uint4*)&sAl[r][sc] = *(const uint4*)&Al[ga];
            *(uint4*)&sBh[r][sc] = *(const uint4*)&Bth[gb];
            *(uint4*)&sBl[r][sc] = *(const uint4*)&Btl[gb];
        }
        __syncthreads();

        #pragma unroll
        for (int kk = 0; kk < 2; ++kk) {       // two K=32 halves of BK=64
            bf16x8 bh[4], bl[4];
            #pragma unroll
            for (int j = 0; j < 4; ++j) {
                const int brow = wc*64 + j*16 + llo;
                const int slot = ((kk*4 + lhi) ^ (brow & 7)) * 8;
                bh[j] = *(const bf16x8*)&sBh[brow][slot];
                bl[j] = *(const bf16x8*)&sBl[brow][slot];
            }
            #pragma unroll
            for (int i = 0; i < 4; ++i) {
                const int arow = wr*64 + i*16 + llo;
                const int slot = ((kk*4 + lhi) ^ (arow & 7)) * 8;
                const bf16x8 ah = *(const bf16x8*)&sAh[arow][slot];
                const bf16x8 al = *(const bf16x8*)&sAl[arow][slot];
                #pragma unroll
                for (int j = 0; j < 4; ++j) {
                    acc[i][j] = __builtin_amdgcn_mfma_f32_16x16x32_bf16(ah, bh[j], acc[i][j], 0, 0, 0);
                    acc[i][j] = __builtin_amdgcn_mfma_f32_16x16x32_bf16(ah, bl[j], acc[i][j], 0, 0, 0);
                    acc[i][j] = __builtin_amdgcn_mfma_f32_16x16x32_bf16(al, bh[j], acc[i][j], 0, 0, 0);
                }
            }
        }
    }

    float bv4[4];
    #pragma unroll
    for (int j = 0; j < 4; ++j)
        bv4[j] = bias[bn + wc*64 + j*16 + llo];

    #pragma unroll
    for (int i = 0; i < 4; ++i) {
        #pragma unroll
        for (int reg = 0; reg < 4; ++reg) {
            const int m = bm + wr*64 + i*16 + lhi*4 + reg;
            #pragma unroll
            for (int j = 0; j < 4; ++j) {
                const int n = bn + wc*64 + j*16 + llo;
                const float val = acc[i][j][reg] + bv4[j];
                if (OUT_MODE == 1) {
                    const int bb = m >> 11, tq = m & (T_SEQ - 1);
                    const int h  = n >> 6,  d  = n & 63;
                    ((ushort*)out)[(((size_t)(bb*N_HEADS + h))*T_SEQ + tq)*H_DIM + d] = f2bf(val);
                } else {
                    ((float*)out)[(size_t)m * C_DIM + n] = val;
                }
            }
        }
    }
}

__global__ __launch_bounds__(256)
void qkv_split_kernel(const ushort* __restrict__ xh, const ushort* __restrict__ xl,
                      const ushort* __restrict__ wth, const ushort* __restrict__ wtl,
                      const float* __restrict__ bq, const float* __restrict__ bk,
                      const float* __restrict__ bv,
                      ushort* __restrict__ q, ushort* __restrict__ k,
                      ushort* __restrict__ v)
{
    const size_t off = (size_t)blockIdx.z * C_DIM * C_DIM;
    const float* bias = (blockIdx.z == 0) ? bq : (blockIdx.z == 1) ? bk : bv;
    ushort* out = (blockIdx.z == 0) ? q : (blockIdx.z == 1) ? k : v;
    split_gemm<1>(xh, xl, wth + off, wtl + off, bias, out);
}

__global__ __launch_bounds__(256)
void out_split_kernel(const ushort* __restrict__ ah, const ushort* __restrict__ al,
                      const ushort* __restrict__ wth, const ushort* __restrict__ wtl,
                      const float* __restrict__ bo, float* __restrict__ out)
{
    split_gemm<0>(ah, al, wth, wtl, bo, out);
}

// ---------------------------------------------------------------------------
// bf16-MFMA flash attention (unchanged structure from Round 7's verified run;
// epilogue now writes att as hi/lo bf16 pair for the split output projection).
// ---------------------------------------------------------------------------
__global__ __launch_bounds__(256)
void attn_kernel(const ushort* __restrict__ q, const ushort* __restrict__ k,
                 const ushort* __restrict__ v,
                 ushort* __restrict__ att_h, ushort* __restrict__ att_l)
{
    __shared__ ushort Qs[64][64];
    __shared__ ushort Ks[64][64];
    __shared__ ushort Vt[64][64];   // transposed: [d][key]
    __shared__ ushort Ps[64][64];

    const int t    = threadIdx.x;
    const int w    = t >> 6;         // wave 0..3
    const int lane = t & 63;
    const int lhi  = lane >> 4;      // 0..3
    const int llo  = lane & 15;      // 0..15
    const int pair = blockIdx.x;     // 0..15
    const int bh   = blockIdx.y;     // b*16 + h
    const int b    = bh >> 4, h = bh & 15;
    const size_t base = (size_t)bh * T_SEQ * H_DIM;

    #pragma unroll 1
    for (int side = 0; side < 2; ++side) {
        const int qt = side ? pair : (31 - pair);
        const int q0 = qt * 64;

        #pragma unroll
        for (int u = 0; u < 2; ++u) {
            const int idx = t*2 + u;
            const int r = idx >> 3, c = idx & 7;
            const uint4 val = *(const uint4*)&q[base + (size_t)(q0 + r)*H_DIM + c*8];
            *(uint4*)&Qs[r][(c ^ (r & 7)) * 8] = val;
        }

        float m_i[4], l_i[4];
        f32x4 o[4];
        #pragma unroll
        for (int i = 0; i < 4; ++i) {
            m_i[i] = -1e30f; l_i[i] = 0.f;
            o[i] = (f32x4){0.f, 0.f, 0.f, 0.f};
        }

        #pragma unroll 1
        for (int j = 0; j <= qt; ++j) {
            __syncthreads();
            #pragma unroll
            for (int u = 0; u < 2; ++u) {
                const int idx = t*2 + u;
                const int r = idx >> 3, c = idx & 7;
                const uint4 kv4 = *(const uint4*)&k[base + (size_t)(j*64 + r)*H_DIM + c*8];
                *(uint4*)&Ks[r][(c ^ (r & 7)) * 8] = kv4;
                const uint4 vv4 = *(const uint4*)&v[base + (size_t)(j*64 + r)*H_DIM + c*8];
                const ushort* ve = (const ushort*)&vv4;
                #pragma unroll
                for (int e = 0; e < 8; ++e) {
                    const int d = c*8 + e;
                    Vt[d][(((r >> 3) ^ (d & 7)) * 8) + (r & 7)] = ve[e];
                }
            }
            __syncthreads();

            bf16x8 af[2];
            {
                const int row = 16*w + llo;
                #pragma unroll
                for (int ds = 0; ds < 2; ++ds)
                    af[ds] = *(const bf16x8*)&Qs[row][((ds*4 + lhi) ^ (row & 7)) * 8];
            }
            f32x4 sacc[4];
            #pragma unroll
            for (int kt = 0; kt < 4; ++kt) {
                sacc[kt] = (f32x4){0.f, 0.f, 0.f, 0.f};
                const int krow = kt*16 + llo;
                #pragma unroll
                for (int ds = 0; ds < 2; ++ds) {
                    const bf16x8 bf = *(const bf16x8*)&Ks[krow][((ds*4 + lhi) ^ (krow & 7)) * 8];
                    sacc[kt] = __builtin_amdgcn_mfma_f32_16x16x32_bf16(af[ds], bf, sacc[kt], 0, 0, 0);
                }
            }

            float p[4][4];
            float rm[4];
            #pragma unroll
            for (int reg = 0; reg < 4; ++reg) {
                const int qr = q0 + 16*w + lhi*4 + reg;
                float tm = -1e30f;
                #pragma unroll
                for (int kt = 0; kt < 4; ++kt) {
                    float sv = sacc[kt][reg] * 0.125f;
                    const int keyg = j*64 + kt*16 + llo;
                    sv = (keyg <= qr) ? sv : -1e30f;
                    p[kt][reg] = sv;
                    tm = fmaxf(tm, sv);
                }
                #pragma unroll
                for (int off = 1; off < 16; off <<= 1)
                    tm = fmaxf(tm, __shfl_xor(tm, off));
                rm[reg] = tm;
            }
            #pragma unroll
            for (int reg = 0; reg < 4; ++reg) {
                const float mn = fmaxf(m_i[reg], rm[reg]);
                const float sc = __expf(m_i[reg] - mn);
                m_i[reg] = mn;
                float acc = 0.f;
                #pragma unroll
                for (int kt = 0; kt < 4; ++kt) {
                    const float pe = __expf(p[kt][reg] - mn);
                    p[kt][reg] = pe;
                    acc += pe;
                }
                #pragma unroll
                for (int off = 1; off < 16; off <<= 1)
                    acc += __shfl_xor(acc, off);
                l_i[reg] = l_i[reg]*sc + acc;
                #pragma unroll
                for (int dt = 0; dt < 4; ++dt)
                    o[dt][reg] *= sc;
            }

            #pragma unroll
            for (int kt = 0; kt < 4; ++kt) {
                #pragma unroll
                for (int reg = 0; reg < 4; ++reg) {
                    const int row = 16*w + lhi*4 + reg;
                    const int key = kt*16 + llo;
                    Ps[row][(((key >> 3) ^ (row & 7)) * 8) + (key & 7)] =
                        f2bf(p[kt][reg]);
                }
            }

            bf16x8 pf[2];
            {
                const int row = 16*w + llo;
                #pragma unroll
                for (int ks = 0; ks < 2; ++ks)
                    pf[ks] = *(const bf16x8*)&Ps[row][((ks*4 + lhi) ^ (row & 7)) * 8];
            }
            #pragma unroll
            for (int dt = 0; dt < 4; ++dt) {
                const int vrow = dt*16 + llo;
                #pragma unroll
                for (int ks = 0; ks < 2; ++ks) {
                    const bf16x8 bf = *(const bf16x8*)&Vt[vrow][((ks*4 + lhi) ^ (vrow & 7)) * 8];
                    o[dt] = __builtin_amdgcn_mfma_f32_16x16x32_bf16(pf[ks], bf, o[dt], 0, 0, 0);
                }
            }
        }

        // ---- normalize + write [B,T,C] as hi/lo bf16 pair
        #pragma unroll
        for (int reg = 0; reg < 4; ++reg) {
            const float inv = 1.0f / l_i[reg];
            const int row = q0 + 16*w + lhi*4 + reg;
            #pragma unroll
            for (int dt = 0; dt < 4; ++dt) {
                const float val = o[dt][reg] * inv;
                const size_t idx = ((size_t)(b*T_SEQ + row))*C_DIM + h*H_DIM + dt*16 + llo;
                const ushort hi = f2bf(val);
                att_h[idx] = hi;
                att_l[idx] = f2bf(val - bf2f(hi));
            }
        }
        __syncthreads();
    }
}

// ---------------------------------------------------------------------------
extern "C" void kernel_launch(void* const* d_in, const int* in_sizes, int n_in,
                              void* d_out, int out_size, void* d_ws, size_t ws_size,
                              hipStream_t stream) {
    (void)in_sizes; (void)n_in; (void)out_size; (void)ws_size;
    const float* x  = (const float*)d_in[0];
    const float* Wq = (const float*)d_in[1];
    const float* bq = (const float*)d_in[2];
    const float* Wk = (const float*)d_in[3];
    const float* bk = (const float*)d_in[4];
    const float* Wv = (const float*)d_in[5];
    const float* bv = (const float*)d_in[6];
    const float* Wo = (const float*)d_in[7];
    const float* bo = (const float*)d_in[8];

    // workspace (56 MB total; ws proven >= 64 MB by Round-1 run):
    //   xh, xl:   [M,C] bf16 hi/lo (8 MB each) -- reused as att_h/att_l
    //   wth, wtl: 4x [N,K] transposed bf16 hi/lo (8 MB each)
    //   q, k, v:  [B,H,T,D] bf16 (8 MB each)
    const size_t MC = (size_t)M_TOT * C_DIM;
    const size_t CC = (size_t)C_DIM * C_DIM;
    ushort* xh  = (ushort*)d_ws;
    ushort* xl  = xh + MC;
    ushort* wth = xl + MC;
    ushort* wtl = wth + 4*CC;
    ushort* q   = wtl + 4*CC;
    ushort* k   = q + MC;
    ushort* v   = k + MC;
    ushort* att_h = xh;   // x dead after qkv projection (stream-ordered)
    ushort* att_l = xl;

    convert_x_kernel<<<(int)(MC/1024), 256, 0, stream>>>(x, xh, xl);
    convert_w_kernel<<<dim3(16, 16, 4), 256, 0, stream>>>(Wq, Wk, Wv, Wo, wth, wtl);

    qkv_split_kernel<<<dim3(8, 32, 3), 256, 0, stream>>>(xh, xl, wth, wtl,
                                                         bq, bk, bv, q, k, v);

    attn_kernel<<<dim3(16, B_SZ*N_HEADS), 256, 0, stream>>>(q, k, v, att_h, att_l);

    out_split_kernel<<<dim3(8, 32), 256, 0, stream>>>(att_h, att_l,
                                                      wth + 3*CC, wtl + 3*CC,
                                                      bo, (float*)d_out);
}